// Round 8
// baseline (390.488 us; speedup 1.0000x reference)
//
#include <hip/hip_runtime.h>
#include <hip/hip_bf16.h>
#include <cstddef>
#include <cstdint>

// Problem constants
#define NB 128
#define NT 4096
#define NC 32
// bits rows: scales {1,16,64,256,1024,4096} -> offsets {0,1,17,81,337,1361}, total 5457
#define BITROWS 5457
#define QV_ROWS 1361          // qv region stride (only row 0 = scale-0 used now)
#define QOUT_ELEMS (NB*NT*NC)             // 16777216
#define BITS_ELEMS (NB*BITROWS*NC)        // 22351872

// ws layout (bytes):
//   qv   @ 0          : NB*1361*32 floats (only row 0 per b written now)
//   acc  @ 22298624   : 204 doubles (ent[6], com[6], p[6][32]) = 1632 B
//   S16  @ 22302720   : NB*256*32 floats = 4,194,304 B
#define ACC_OFF  22298624
#define S16_OFF  22302720

__device__ __constant__ float kQSC = 0.17677669529663687f;   // 1/sqrt(32)
__device__ __constant__ float kSIG = 17.67766952966369f;     // 100/sqrt(32)

// reference interp against an LDS slice whose row 0 is global coarse row `base`
// (base may be negative; lo>=0 always so indices stay in range). Exact: no fma.
__device__ __forceinline__ float interp_slice(const float* __restrict__ q, int P, int base, int t, int c) {
  float pos = ((float)t + 0.5f) * ((float)P * (1.0f / 4096.0f)) - 0.5f;
  pos = fminf(fmaxf(pos, 0.0f), (float)(P - 1));
  const int lo = (int)pos;
  const int hi = min(lo + 1, P - 1);
  const float w = pos - (float)lo;
  const float a = __fmul_rn(q[(lo - base) * NC + c], 1.0f - w);
  const float b = __fmul_rn(q[(hi - base) * NC + c], w);
  return __fadd_rn(a, b);
}

// per-coarse-element: normalize over C (32 lanes), sign-quantize, write qv/bits, loss elems
// qlsRow / qvG are nullable (compile-time constant null folds the store away).
__device__ __forceinline__ void process_elem(
    float msum, float invn, int b, int rowOff, int j, int c,
    float* qlsRow, float* __restrict__ qvG, float* __restrict__ bitsG,
    float& entA, float& comA, float& pA)
{
  const float m = msum * invn;       // invn is a power of two -> exact
  float ss = m * m;
  #pragma unroll
  for (int mk = 16; mk; mk >>= 1) ss += __shfl_xor(ss, mk, 32);
  const float den = fmaxf(sqrtf(ss), 1e-12f);
  const float fn = m / den;
  const bool bit = fn > 0.0f;
  const float zh = bit ? kQSC : -kQSC;
  const float qvv = fn + (zh - fn);  // reference: quantized = f + (zhat - f)
  if (qlsRow) qlsRow[c] = qvv;
  if (qvG) qvG[(size_t)b * (QV_ROWS * NC) + (size_t)(rowOff + j) * NC + c] = qvv;
  bitsG[(size_t)b * (BITROWS * NC) + (size_t)(rowOff + j) * NC + c] = bit ? 1.0f : 0.0f;
  const float arg = (-4.0f * fn) * kSIG;         // sigmoid(-4*f*100/sqrt(32))
  const float p = 1.0f / (1.0f + __expf(-arg));
  const float ent = -(p * __logf(p + 1e-8f) + (1.0f - p) * __logf((1.0f - p) + 1e-8f));
  const float d = qvv - fn;
  entA += ent; comA += d * d; pA += p;
}

// halo version: same quantize chain, no side effects, returns qvv
__device__ __forceinline__ float quant_silent(float msum, float invn) {
  const float m = msum * invn;
  float ss = m * m;
  #pragma unroll
  for (int mk = 16; mk; mk >>= 1) ss += __shfl_xor(ss, mk, 32);
  const float den = fmaxf(sqrtf(ss), 1e-12f);
  const float fn = m / den;
  const float zh = (fn > 0.0f) ? kQSC : -kQSC;
  return fn + (zh - fn);
}

// block-level loss reduction -> double atomics. all threads must call.
__device__ __forceinline__ void reduce_losses(
    int sIdx, float entA, float comA, float pA, int tid, int nWaves,
    double* __restrict__ acc, float* redE, float* redC, float* redP)
{
  float e = entA, cm = comA;
  #pragma unroll
  for (int mk = 32; mk; mk >>= 1) { e += __shfl_xor(e, mk, 64); cm += __shfl_xor(cm, mk, 64); }
  const float p = pA + __shfl_xor(pA, 32, 64);
  const int w = tid >> 6, lane = tid & 63;
  if (lane == 0) { redE[w] = e; redC[w] = cm; }
  if (lane < 32) redP[w * 32 + lane] = p;
  __syncthreads();
  if (tid == 0) {
    double te = 0.0, tc = 0.0;
    for (int i = 0; i < nWaves; ++i) { te += (double)redE[i]; tc += (double)redC[i]; }
    atomicAdd(&acc[sIdx], te);
    atomicAdd(&acc[6 + sIdx], tc);
  }
  if (tid < 32) {
    float tp = 0.0f;
    for (int i = 0; i < nWaves; ++i) tp += redP[i * 32 + tid];
    atomicAdd(&acc[12 + sIdx * 32 + tid], (double)tp);
  }
  __syncthreads();
}

// ---------- P0: granularity-16 sums of f (t-ascending, blocked-sequential) ----------
__global__ __launch_bounds__(256) void k_sum16(const float* __restrict__ f, float* __restrict__ S16) {
  const int idx = blockIdx.x * 256 + threadIdx.x;   // NB*256*32 = 1,048,576
  if (idx >= NB * 256 * NC) return;
  const int c = idx & 31;
  const int j = (idx >> 5) & 255;
  const int b = idx >> 13;
  const float* p = f + (size_t)b * (NT * NC) + (size_t)j * 16 * NC + c;
  float s = 0.0f;
  #pragma unroll
  for (int k = 0; k < 16; ++k) s += p[k * NC];
  S16[idx] = s;
}

// ---------- P1: scale 0 (pt=1) — deterministic global-T reduction per b ----------
__global__ __launch_bounds__(1024) void k_s0(
    const float* __restrict__ S16g, float* __restrict__ qv,
    float* __restrict__ bitsOut, double* __restrict__ acc)
{
  __shared__ float red[1024];
  __shared__ float redE[16], redC[16], redP[16 * 32];
  const int b = blockIdx.x, tid = threadIdx.x, c = tid & 31;
  const float* __restrict__ sb = S16g + (size_t)b * 8192;
  {
    const int g = tid >> 5;
    float part = 0.0f;
    #pragma unroll
    for (int j = 0; j < 8; ++j) part += sb[(size_t)(g * 8 + j) * NC + c];
    red[tid] = part;
  }
  __syncthreads();
  float entA = 0.0f, comA = 0.0f, pA = 0.0f;
  if (tid < 32) {
    float msum = 0.0f;
    for (int g = 0; g < 32; ++g) msum += red[g * 32 + tid];
    process_elem(msum, 1.0f / 4096.0f, b, 0, 0, tid, nullptr, qv, bitsOut, entA, comA, pA);
  }
  reduce_losses(0, entA, comA, pA, tid, 16, acc, redE, redC, redP);
}

// ---------- P2: scales 1..5 fully fused per 256-t tile ----------
// Stage the 48-row S16 window [16seg-16, 16seg+32); compute scale-1/2/3 rows
// locally (own rows: bits+losses; halo rows: quant_silent — identical chains,
// identical values as the owner tile computes). The halo q-row sets are exactly
// the ql1/ql2/ql3 slices the old k_s45 loaded from global qv. Then the R7
// 1-pass-pipelined Phase A (scale 4) + Phase B (scale 5).
// All bits/qout-determining arithmetic bit-identical to the previous rounds;
// only loss partial-sum grouping changes (double-atomic level; benign R3-R7).
__global__ __launch_bounds__(256) void k_fused(
    const float* __restrict__ f, const float* __restrict__ S16g,
    const float* __restrict__ qv, float* __restrict__ qout,
    float* __restrict__ bitsOut, double* __restrict__ acc)
{
  __shared__ float S[48 * NC];         // S16 rows [16seg-16, 16seg+32), 6 KB
  __shared__ float q1s[3 * NC];        // scale-1 rows [seg-1, seg+2)
  __shared__ float q2s[6 * NC];        // scale-2 rows [4seg-1, 4seg+5)
  __shared__ float q3s[18 * NC];       // scale-3 rows [16seg-1, 16seg+17)
  __shared__ float ql4[66 * NC];       // scale-4 rows [64seg-1, 64seg+65)
  __shared__ float redE[4], redC[4], redP[4 * 32];
  const int b = blockIdx.x >> 4, seg = blockIdx.x & 15;
  const int tid = threadIdx.x, c = tid & 31, rloc = tid >> 5;   // rloc in [0,8)
  const float* __restrict__ fb = f + (size_t)b * (NT * NC);
  const float* __restrict__ sb = S16g + (size_t)b * 8192;
  const int b1 = seg - 1, b2 = 4 * seg - 1, b3 = 16 * seg - 1, b4 = 64 * seg - 1;
  const int srow0 = 16 * seg - 16;
  const float q0v = qv[(size_t)b * (QV_ROWS * NC) + c];   // scale-0 q (row 0), lane channel

  // stage S16 window + scale-0 subtraction (same per-element ops as before)
  for (int e = tid; e < 48 * NC; e += 256) {
    const int rw = min(max(srow0 + (e >> 5), 0), 255);    // clamped slots are never read
    S[e] = sb[(size_t)rw * NC + (e & 31)] - 16.0f * q0v;
  }
  __syncthreads();

  float ent = 0.0f, com = 0.0f, pp = 0.0f;

  // ----- scale 1 (pt=16): own row seg + silent halos seg-1, seg+1 -----
  if (tid < 3 * NC) {
    const int r = tid >> 5, j = b1 + r;
    if (j >= 0 && j < 16) {
      float msum = 0.0f;
      for (int jj = 0; jj < 16; ++jj) msum += S[(j * 16 + jj - srow0) * NC + c];
      if (r == 1)  // j == seg
        process_elem(msum, 1.0f / 256.0f, b, 1, j, c, &q1s[r * NC], nullptr, bitsOut, ent, com, pp);
      else
        q1s[r * NC + c] = quant_silent(msum, 1.0f / 256.0f);
    }
  }
  reduce_losses(1, ent, com, pp, tid, 4, acc, redE, redC, redP);   // also publishes q1s

  // scale-1 correction on S rows [16seg-4, 16seg+20) (feeds scale-2 own+halo)
  for (int e = tid; e < 24 * NC; e += 256) {
    const int g = 16 * seg - 4 + (e >> 5);
    if (g >= 0 && g < 256) {
      float cs = 0.0f;
      #pragma unroll
      for (int k = 0; k < 16; ++k) cs += interp_slice(q1s, 16, b1, g * 16 + k, c);
      S[(g - srow0) * NC + c] -= cs;
    }
  }
  __syncthreads();

  // ----- scale 2 (pt=64): own rows [4seg,4seg+4) + silent halos 4seg-1, 4seg+4 -----
  ent = com = pp = 0.0f;
  if (tid < 6 * NC) {
    const int r = tid >> 5, j2 = b2 + r;
    if (j2 >= 0 && j2 < 64) {
      float msum = 0.0f;
      #pragma unroll
      for (int jj = 0; jj < 4; ++jj) msum += S[(j2 * 4 + jj - srow0) * NC + c];
      if (r >= 1 && r <= 4)   // j2 in [4seg, 4seg+4)
        process_elem(msum, 1.0f / 64.0f, b, 17, j2, c, &q2s[r * NC], nullptr, bitsOut, ent, com, pp);
      else
        q2s[r * NC + c] = quant_silent(msum, 1.0f / 64.0f);
    }
  }
  reduce_losses(2, ent, com, pp, tid, 4, acc, redE, redC, redP);   // publishes q2s

  // scale-2 correction on S rows [16seg-1, 16seg+17) (feeds scale-3 own+halo)
  for (int e = tid; e < 18 * NC; e += 256) {
    const int g = 16 * seg - 1 + (e >> 5);
    if (g >= 0 && g < 256) {
      float cs = 0.0f;
      #pragma unroll
      for (int k = 0; k < 16; ++k) cs += interp_slice(q2s, 64, b2, g * 16 + k, c);
      S[(g - srow0) * NC + c] -= cs;
    }
  }
  __syncthreads();

  // ----- scale 3 (pt=256): own rows [16seg,16seg+16) + silent halos 16seg-1, 16seg+16 -----
  ent = com = pp = 0.0f;
  for (int e = tid; e < 18 * NC; e += 256) {
    const int r = e >> 5, g = b3 + r;
    if (g >= 0 && g < 256) {
      const float ms = S[(g - srow0) * NC + c];
      if (r >= 1 && r <= 16)  // g in [16seg, 16seg+16)
        process_elem(ms, 1.0f / 16.0f, b, 81, g, c, &q3s[r * NC], nullptr, bitsOut, ent, com, pp);
      else
        q3s[r * NC + c] = quant_silent(ms, 1.0f / 16.0f);
    }
  }
  reduce_losses(3, ent, com, pp, tid, 4, acc, redE, redC, redP);   // publishes q3s

  // ----- scales 4+5: R7 1-pass software pipeline -----
  float entA4 = 0.0f, comA4 = 0.0f, pA4 = 0.0f;
  float entB = 0.0f, comB = 0.0f, pB = 0.0f;

  auto do_A = [&](int p, float rc[4], float qc[4]) {
    const int i = seg * 64 + p * 8 + rloc;
    const float* fp = fb + (size_t)i * 4 * NC + c;
    float msum = 0.0f;
    #pragma unroll
    for (int k = 0; k < 4; ++k) {
      const int t = i * 4 + k;
      const float q0 = q0v;                               // exact: P=1 interp == q[c]
      const float q1 = interp_slice(q1s, 16,  b1, t, c);
      const float q2 = interp_slice(q2s, 64,  b2, t, c);
      const float q3 = interp_slice(q3s, 256, b3, t, c);
      float r = fp[k * NC];
      r -= q0; r -= q1; r -= q2; r -= q3;                 // exact reference chain prefix
      float qs = q0; qs += q1; qs += q2; qs += q3;        // exact reference qout prefix
      rc[k] = r; qc[k] = qs;
      msum += r;                                          // sequential t-order
    }
    process_elem(msum, 0.25f, b, 337, i, c,
                 &ql4[(size_t)(i - b4) * NC], nullptr, bitsOut, entA4, comA4, pA4);
  };

  auto do_halo = [&](int hr) {
    const float* fp = fb + (size_t)hr * 4 * NC + c;
    float msum = 0.0f;
    #pragma unroll
    for (int k = 0; k < 4; ++k) {
      const int t = hr * 4 + k;
      float r = fp[k * NC];
      r -= q0v;
      r -= interp_slice(q1s, 16,  b1, t, c);
      r -= interp_slice(q2s, 64,  b2, t, c);
      r -= interp_slice(q3s, 256, b3, t, c);
      msum += r;
    }
    ql4[(size_t)(hr - b4) * NC + c] = quant_silent(msum, 0.25f);
  };

  auto do_B = [&](int p, const float rc[4], const float qc[4]) {
    const int i = seg * 64 + p * 8 + rloc;
    #pragma unroll
    for (int k = 0; k < 4; ++k) {
      const int t = i * 4 + k;
      const float q4 = interp_slice(ql4, 1024, b4, t, c);
      float r = rc[k];
      r -= q4;                                            // completes exact chain: fv-q0..-q4
      float qs = qc[k];
      qs += q4;                                           // completes exact qout sum order
      float ss = r * r;
      #pragma unroll
      for (int mk = 16; mk; mk >>= 1) ss += __shfl_xor(ss, mk, 32);
      const float den = fmaxf(sqrtf(ss), 1e-12f);
      const float fn = r / den;
      const bool bit = fn > 0.0f;
      const float zh = bit ? kQSC : -kQSC;
      const float qvv = fn + (zh - fn);
      qout[(size_t)b * (NT * NC) + (size_t)t * NC + c] = qs + qvv;
      bitsOut[(size_t)b * (BITROWS * NC) + (size_t)(1361 + t) * NC + c] = bit ? 1.0f : 0.0f;
      const float arg = (-4.0f * fn) * kSIG;
      const float p2 = 1.0f / (1.0f + __expf(-arg));
      entB += -(p2 * __logf(p2 + 1e-8f) + (1.0f - p2) * __logf((1.0f - p2) + 1e-8f));
      const float d = qvv - fn;
      comB += d * d;
      pB += p2;
    }
  };

  float rAp[4], qsAp[4];           // prev-pass carry
  float rAc[4], qsAc[4];           // current-pass carry

  do_A(0, rAp, qsAp);
  if (rloc == 0 && seg > 0) do_halo(64 * seg - 1);        // left halo (with pass 0)

  for (int p = 1; p < 8; ++p) {
    do_A(p, rAc, qsAc);
    __syncthreads();               // ql4 rows of pass p (and p-1) visible
    do_B(p - 1, rAp, qsAp);
    #pragma unroll
    for (int k = 0; k < 4; ++k) { rAp[k] = rAc[k]; qsAp[k] = qsAc[k]; }
  }
  if (rloc == 1 && seg < 15) do_halo(64 * seg + 64);      // right halo (before last B)
  __syncthreads();
  do_B(7, rAp, qsAp);

  reduce_losses(4, entA4, comA4, pA4, tid, 4, acc, redE, redC, redP);
  reduce_losses(5, entB, comB, pB, tid, 4, acc, redE, redC, redP);
}

// ---------- P4: finalize 6 scalar losses ----------
__global__ void k_losses(const double* __restrict__ acc, float* __restrict__ out) {
  const int s = threadIdx.x;
  if (s >= 6) return;
  const int pts[6] = {1, 16, 64, 256, 1024, 4096};
  const double n = 128.0 * (double)pts[s];
  const double pse = acc[s] / n;
  const double commit = acc[6 + s] / n;
  double cbe = 0.0;
  for (int c = 0; c < 32; ++c) {
    const double ap = acc[12 + s * 32 + c] / n;
    cbe += -(ap * log(ap + 1e-8) + (1.0 - ap) * log((1.0 - ap) + 1e-8));
  }
  const double pen = (pse - cbe) / 100.0;
  out[s] = (float)(pen * 0.1 + commit * 0.2);
}

extern "C" void kernel_launch(void* const* d_in, const int* in_sizes, int n_in,
                              void* d_out, int out_size, void* d_ws, size_t ws_size,
                              hipStream_t stream) {
  const float* f = (const float*)d_in[0];
  float* qout = (float*)d_out;
  float* bitsOut = qout + QOUT_ELEMS;
  float* lossesOut = qout + (QOUT_ELEMS + BITS_ELEMS);
  float* qv = (float*)d_ws;
  double* acc = (double*)((char*)d_ws + ACC_OFF);
  float* S16 = (float*)((char*)d_ws + S16_OFF);

  hipMemsetAsync(acc, 0, 204 * sizeof(double), stream);
  k_sum16<<<4096, 256, 0, stream>>>(f, S16);
  k_s0<<<NB, 1024, 0, stream>>>(S16, qv, bitsOut, acc);
  k_fused<<<NB * 16, 256, 0, stream>>>(f, S16, qv, qout, bitsOut, acc);
  k_losses<<<1, 64, 0, stream>>>(acc, lossesOut);
}

// Round 9
// 320.637 us; speedup vs baseline: 1.2178x; 1.2178x over previous
//
#include <hip/hip_runtime.h>
#include <hip/hip_bf16.h>
#include <cstddef>
#include <cstdint>

// Problem constants
#define NB 128
#define NT 4096
#define NC 32
// bits rows: scales {1,16,64,256,1024,4096} -> offsets {0,1,17,81,337,1361}, total 5457
#define BITROWS 5457
#define QV_ROWS 1361          // qv region stride (rows 0..336 written)
#define QOUT_ELEMS (NB*NT*NC)             // 16777216
#define BITS_ELEMS (NB*BITROWS*NC)        // 22351872

// ws layout (bytes):
//   qv   @ 0          : NB*1361*32 floats (rows 0..336 per b written)
//   acc  @ 22298624   : 204 doubles (ent[6], com[6], p[6][32]) = 1632 B
//   S16  @ 22302720   : NB*256*32 floats = 4,194,304 B
#define ACC_OFF  22298624
#define S16_OFF  22302720

__device__ __constant__ float kQSC = 0.17677669529663687f;   // 1/sqrt(32)
__device__ __constant__ float kSIG = 17.67766952966369f;     // 100/sqrt(32)

// reference interp against an LDS slice whose row 0 is global coarse row `base`
// (base may be negative; lo>=0 always so indices stay in range). Exact: no fma.
__device__ __forceinline__ float interp_slice(const float* __restrict__ q, int P, int base, int t, int c) {
  float pos = ((float)t + 0.5f) * ((float)P * (1.0f / 4096.0f)) - 0.5f;
  pos = fminf(fmaxf(pos, 0.0f), (float)(P - 1));
  const int lo = (int)pos;
  const int hi = min(lo + 1, P - 1);
  const float w = pos - (float)lo;
  const float a = __fmul_rn(q[(lo - base) * NC + c], 1.0f - w);
  const float b = __fmul_rn(q[(hi - base) * NC + c], w);
  return __fadd_rn(a, b);
}

// per-coarse-element: normalize over C (32 lanes), sign-quantize, write qv/bits, loss elems
// qlsRow / qvG are nullable (compile-time constant null folds the store away).
__device__ __forceinline__ void process_elem(
    float msum, float invn, int b, int rowOff, int j, int c,
    float* qlsRow, float* __restrict__ qvG, float* __restrict__ bitsG,
    float& entA, float& comA, float& pA)
{
  const float m = msum * invn;       // invn is a power of two -> exact
  float ss = m * m;
  #pragma unroll
  for (int mk = 16; mk; mk >>= 1) ss += __shfl_xor(ss, mk, 32);
  const float den = fmaxf(sqrtf(ss), 1e-12f);
  const float fn = m / den;
  const bool bit = fn > 0.0f;
  const float zh = bit ? kQSC : -kQSC;
  const float qvv = fn + (zh - fn);  // reference: quantized = f + (zhat - f)
  if (qlsRow) qlsRow[c] = qvv;
  if (qvG) qvG[(size_t)b * (QV_ROWS * NC) + (size_t)(rowOff + j) * NC + c] = qvv;
  bitsG[(size_t)b * (BITROWS * NC) + (size_t)(rowOff + j) * NC + c] = bit ? 1.0f : 0.0f;
  const float arg = (-4.0f * fn) * kSIG;         // sigmoid(-4*f*100/sqrt(32))
  const float p = 1.0f / (1.0f + __expf(-arg));
  const float ent = -(p * __logf(p + 1e-8f) + (1.0f - p) * __logf((1.0f - p) + 1e-8f));
  const float d = qvv - fn;
  entA += ent; comA += d * d; pA += p;
}

// halo version: same quantize chain, no side effects, returns qvv
__device__ __forceinline__ float quant_silent(float msum, float invn) {
  const float m = msum * invn;
  float ss = m * m;
  #pragma unroll
  for (int mk = 16; mk; mk >>= 1) ss += __shfl_xor(ss, mk, 32);
  const float den = fmaxf(sqrtf(ss), 1e-12f);
  const float fn = m / den;
  const float zh = (fn > 0.0f) ? kQSC : -kQSC;
  return fn + (zh - fn);
}

// block-level loss reduction -> double atomics. all threads must call.
__device__ __forceinline__ void reduce_losses(
    int sIdx, float entA, float comA, float pA, int tid, int nWaves,
    double* __restrict__ acc, float* redE, float* redC, float* redP)
{
  float e = entA, cm = comA;
  #pragma unroll
  for (int mk = 32; mk; mk >>= 1) { e += __shfl_xor(e, mk, 64); cm += __shfl_xor(cm, mk, 64); }
  const float p = pA + __shfl_xor(pA, 32, 64);
  const int w = tid >> 6, lane = tid & 63;
  if (lane == 0) { redE[w] = e; redC[w] = cm; }
  if (lane < 32) redP[w * 32 + lane] = p;
  __syncthreads();
  if (tid == 0) {
    double te = 0.0, tc = 0.0;
    for (int i = 0; i < nWaves; ++i) { te += (double)redE[i]; tc += (double)redC[i]; }
    atomicAdd(&acc[sIdx], te);
    atomicAdd(&acc[6 + sIdx], tc);
  }
  if (tid < 32) {
    float tp = 0.0f;
    for (int i = 0; i < nWaves; ++i) tp += redP[i * 32 + tid];
    atomicAdd(&acc[12 + sIdx * 32 + tid], (double)tp);
  }
  __syncthreads();
}

// ---------- P0: granularity-16 sums of f (t-ascending, blocked-sequential) ----------
__global__ __launch_bounds__(256) void k_sum16(const float* __restrict__ f, float* __restrict__ S16) {
  const int idx = blockIdx.x * 256 + threadIdx.x;   // NB*256*32 = 1,048,576
  if (idx >= NB * 256 * NC) return;
  const int c = idx & 31;
  const int j = (idx >> 5) & 255;
  const int b = idx >> 13;
  const float* p = f + (size_t)b * (NT * NC) + (size_t)j * 16 * NC + c;
  float s = 0.0f;
  #pragma unroll
  for (int k = 0; k < 16; ++k) s += p[k * NC];
  S16[idx] = s;
}

// ---------- P1a: scale 0 (pt=1) — deterministic global-T reduction per b ----------
__global__ __launch_bounds__(1024) void k_s0(
    const float* __restrict__ S16g, float* __restrict__ qv,
    float* __restrict__ bitsOut, double* __restrict__ acc)
{
  __shared__ float red[1024];
  __shared__ float redE[16], redC[16], redP[16 * 32];
  const int b = blockIdx.x, tid = threadIdx.x, c = tid & 31;
  const float* __restrict__ sb = S16g + (size_t)b * 8192;
  {
    const int g = tid >> 5;
    float part = 0.0f;
    #pragma unroll
    for (int j = 0; j < 8; ++j) part += sb[(size_t)(g * 8 + j) * NC + c];
    red[tid] = part;
  }
  __syncthreads();
  float entA = 0.0f, comA = 0.0f, pA = 0.0f;
  if (tid < 32) {
    float msum = 0.0f;
    for (int g = 0; g < 32; ++g) msum += red[g * 32 + tid];
    process_elem(msum, 1.0f / 4096.0f, b, 0, 0, tid, nullptr, qv, bitsOut, entA, comA, pA);
  }
  reduce_losses(0, entA, comA, pA, tid, 16, acc, redE, redC, redP);
}

// ---------- P1b: scales 1..3, FOUR blocks per batch element ----------
// seg in [0,4) owns scale-1 rows [4seg,4seg+4), scale-2 [16seg,16seg+16),
// scale-3 [64seg,64seg+64). S window = rows [64seg-16, 64seg+80) (96 rows).
// +-1 boundary q-rows at scale-1/scale-2 are recomputed silently with the
// owner's exact arithmetic. Correction ranges cover exactly what downstream
// sums read. Grid 512 = 2 blocks/CU -> barrier stalls overlap across blocks.
// All per-element chains bit-identical to the 2-seg version; only loss
// partial-sum grouping changes (double-atomic level; benign R3-R7).
__global__ __launch_bounds__(1024) void k_coarse4(
    const float* __restrict__ S16g,
    float* __restrict__ qv, float* __restrict__ bitsOut, double* __restrict__ acc)
{
  __shared__ float S[96 * NC];         // rows [64seg-16, 64seg+80), 12 KB
  __shared__ float q1s[6 * NC];        // scale-1 rows [4seg-1, 4seg+5)
  __shared__ float q2s[18 * NC];       // scale-2 rows [16seg-1, 16seg+17)
  __shared__ float redE[16], redC[16], redP[16 * 32];
  const int b = blockIdx.x >> 2, seg = blockIdx.x & 3;
  const int tid = threadIdx.x, c = tid & 31;
  const int s0r = 64 * seg - 16;       // window start (may be negative; clamped slots unread)
  const int base1 = 4 * seg - 1, base2 = 16 * seg - 1;
  const float* __restrict__ sb = S16g + (size_t)b * 8192;
  const float* __restrict__ qb = qv + (size_t)b * (QV_ROWS * NC);

  // stage window + scale-0 subtraction (same single subtract as before)
  const float corr = 16.0f * qb[c];
  for (int e = tid; e < 96 * NC; e += 1024) {
    const int rw = min(max(s0r + (e >> 5), 0), 255);
    S[e] = sb[(size_t)rw * NC + (e & 31)] - corr;
  }
  __syncthreads();

  float ent, com, pp;

  // ----- scale 1 (pt=16): 4 own rows + silent halos 4seg-1, 4seg+4 -----
  ent = com = pp = 0.0f;
  if (tid < 6 * NC) {
    const int r = tid >> 5, j = base1 + r;
    if (j >= 0 && j < 16) {
      float msum = 0.0f;
      for (int jj = 0; jj < 16; ++jj) msum += S[(j * 16 + jj - s0r) * NC + c];
      if (r >= 1 && r <= 4)   // own rows [4seg, 4seg+4)
        process_elem(msum, 1.0f / 256.0f, b, 1, j, c, &q1s[r * NC], qv, bitsOut, ent, com, pp);
      else
        q1s[r * NC + c] = quant_silent(msum, 1.0f / 256.0f);
    }
  }
  reduce_losses(1, ent, com, pp, tid, 16, acc, redE, redC, redP);   // publishes q1s

  // scale-1 correction on S rows [64seg-4, 64seg+68) (feeds scale-2 own+halo sums)
  for (int e = tid; e < 72 * NC; e += 1024) {
    const int g = 64 * seg - 4 + (e >> 5);
    if (g >= 0 && g < 256) {
      float cs = 0.0f;
      #pragma unroll
      for (int k = 0; k < 16; ++k) cs += interp_slice(q1s, 16, base1, g * 16 + k, c);
      S[(g - s0r) * NC + c] -= cs;
    }
  }
  __syncthreads();

  // ----- scale 2 (pt=64): 16 own rows + silent halos 16seg-1, 16seg+16 -----
  ent = com = pp = 0.0f;
  if (tid < 18 * NC) {
    const int r = tid >> 5, j2 = base2 + r;
    if (j2 >= 0 && j2 < 64) {
      float msum = 0.0f;
      #pragma unroll
      for (int jj = 0; jj < 4; ++jj) msum += S[(j2 * 4 + jj - s0r) * NC + c];
      if (r >= 1 && r <= 16)  // own rows [16seg, 16seg+16)
        process_elem(msum, 1.0f / 64.0f, b, 17, j2, c, &q2s[r * NC], qv, bitsOut, ent, com, pp);
      else
        q2s[r * NC + c] = quant_silent(msum, 1.0f / 64.0f);
    }
  }
  reduce_losses(2, ent, com, pp, tid, 16, acc, redE, redC, redP);   // publishes q2s

  // scale-2 correction on own S rows [64seg, 64seg+64) (feeds scale-3 own rows)
  for (int e = tid; e < 64 * NC; e += 1024) {
    const int g = 64 * seg + (e >> 5);
    float cs = 0.0f;
    #pragma unroll
    for (int k = 0; k < 16; ++k) cs += interp_slice(q2s, 64, base2, g * 16 + k, c);
    S[(g - s0r) * NC + c] -= cs;
  }
  __syncthreads();

  // ----- scale 3 (pt=256): 64 own rows -----
  ent = com = pp = 0.0f;
  for (int out = tid; out < 64 * NC; out += 1024) {
    const int g = 64 * seg + (out >> 5);
    process_elem(S[(g - s0r) * NC + c], 1.0f / 16.0f, b, 81, g, c, nullptr, qv, bitsOut, ent, com, pp);
  }
  reduce_losses(3, ent, com, pp, tid, 16, acc, redE, redC, redP);
}

// ---------- P2: scales 4+5 fused, 256 threads, 1-pass software pipeline (R7) ----------
__global__ __launch_bounds__(256) void k_s45(
    const float* __restrict__ f, const float* __restrict__ qv,
    float* __restrict__ qout, float* __restrict__ bitsOut, double* __restrict__ acc)
{
  __shared__ float ql0[NC];            // scale0 (P=1): interp == ql0[c] exactly
  __shared__ float ql1[3 * NC];        // scale1 rows [seg-1, seg+1] clamped
  __shared__ float ql2[6 * NC];        // scale2 rows [4seg-1, 4seg+4] clamped
  __shared__ float ql3[18 * NC];       // scale3 rows [16seg-1, 16seg+16] clamped
  __shared__ float ql4[66 * NC];       // scale4 rows [64seg-1, 64seg+64]
  __shared__ float redE[4], redC[4], redP[4 * 32];
  const int b = blockIdx.x >> 4, seg = blockIdx.x & 15;
  const int tid = threadIdx.x, c = tid & 31, rloc = tid >> 5;   // rloc in [0,8)
  const float* __restrict__ qb = qv + (size_t)b * (QV_ROWS * NC);
  const float* __restrict__ fb = f + (size_t)b * (NT * NC);
  const int b1 = seg - 1, b2 = 4 * seg - 1, b3 = 16 * seg - 1, b4 = 64 * seg - 1;
  if (tid < NC) ql0[tid] = qb[tid];
  for (int e = tid; e < 3 * NC; e += 256) {
    const int r = min(max(b1 + (e >> 5), 0), 15);
    ql1[e] = qb[(1 + r) * NC + (e & 31)];
  }
  for (int e = tid; e < 6 * NC; e += 256) {
    const int r = min(max(b2 + (e >> 5), 0), 63);
    ql2[e] = qb[(17 + r) * NC + (e & 31)];
  }
  for (int e = tid; e < 18 * NC; e += 256) {
    const int r = min(max(b3 + (e >> 5), 0), 255);
    ql3[e] = qb[(81 + r) * NC + (e & 31)];
  }
  __syncthreads();

  float entA4 = 0.0f, comA4 = 0.0f, pA4 = 0.0f;   // scale-4 losses
  float entB = 0.0f, comB = 0.0f, pB = 0.0f;      // scale-5 losses

  // Phase-A body: scale-4 row for pass p; fills rc/qc (chain prefixes)
  auto do_A = [&](int p, float rc[4], float qc[4]) {
    const int i = seg * 64 + p * 8 + rloc;
    const float* fp = fb + (size_t)i * 4 * NC + c;
    float msum = 0.0f;
    #pragma unroll
    for (int k = 0; k < 4; ++k) {
      const int t = i * 4 + k;
      const float q0 = ql0[c];                            // exact: P=1 interp == q[c]
      const float q1 = interp_slice(ql1, 16,  b1, t, c);
      const float q2 = interp_slice(ql2, 64,  b2, t, c);
      const float q3 = interp_slice(ql3, 256, b3, t, c);
      float r = fp[k * NC];
      r -= q0; r -= q1; r -= q2; r -= q3;                 // exact reference chain prefix
      float qs = q0; qs += q1; qs += q2; qs += q3;        // exact reference qout prefix
      rc[k] = r; qc[k] = qs;
      msum += r;                                          // sequential t-order
    }
    process_elem(msum, 0.25f, b, 337, i, c,
                 &ql4[(size_t)(i - b4) * NC], nullptr, bitsOut, entA4, comA4, pA4);
  };

  // halo row: pure compute into LDS, no bits/loss side effects
  auto do_halo = [&](int hr) {
    const float* fp = fb + (size_t)hr * 4 * NC + c;
    float msum = 0.0f;
    #pragma unroll
    for (int k = 0; k < 4; ++k) {
      const int t = hr * 4 + k;
      float r = fp[k * NC];
      r -= ql0[c];
      r -= interp_slice(ql1, 16,  b1, t, c);
      r -= interp_slice(ql2, 64,  b2, t, c);
      r -= interp_slice(ql3, 256, b3, t, c);
      msum += r;
    }
    ql4[(size_t)(hr - b4) * NC + c] = quant_silent(msum, 0.25f);
  };

  // Phase-B body: scale-5 for pass p using carried prefixes
  auto do_B = [&](int p, const float rc[4], const float qc[4]) {
    const int i = seg * 64 + p * 8 + rloc;
    #pragma unroll
    for (int k = 0; k < 4; ++k) {
      const int t = i * 4 + k;
      const float q4 = interp_slice(ql4, 1024, b4, t, c);
      float r = rc[k];
      r -= q4;                                            // completes exact chain: fv-q0..-q4
      float qs = qc[k];
      qs += q4;                                           // completes exact qout sum order
      float ss = r * r;
      #pragma unroll
      for (int mk = 16; mk; mk >>= 1) ss += __shfl_xor(ss, mk, 32);
      const float den = fmaxf(sqrtf(ss), 1e-12f);
      const float fn = r / den;
      const bool bit = fn > 0.0f;
      const float zh = bit ? kQSC : -kQSC;
      const float qvv = fn + (zh - fn);
      qout[(size_t)b * (NT * NC) + (size_t)t * NC + c] = qs + qvv;
      bitsOut[(size_t)b * (BITROWS * NC) + (size_t)(1361 + t) * NC + c] = bit ? 1.0f : 0.0f;
      const float arg = (-4.0f * fn) * kSIG;
      const float p2 = 1.0f / (1.0f + __expf(-arg));
      entB += -(p2 * __logf(p2 + 1e-8f) + (1.0f - p2) * __logf((1.0f - p2) + 1e-8f));
      const float d = qvv - fn;
      comB += d * d;
      pB += p2;
    }
  };

  float rAp[4], qsAp[4];           // prev-pass carry
  float rAc[4], qsAc[4];           // current-pass carry

  do_A(0, rAp, qsAp);
  if (rloc == 0 && seg > 0) do_halo(64 * seg - 1);        // left halo (with pass 0)

  for (int p = 1; p < 8; ++p) {
    do_A(p, rAc, qsAc);
    __syncthreads();               // ql4 rows of pass p (and p-1) visible
    do_B(p - 1, rAp, qsAp);
    #pragma unroll
    for (int k = 0; k < 4; ++k) { rAp[k] = rAc[k]; qsAp[k] = qsAc[k]; }
  }
  if (rloc == 1 && seg < 15) do_halo(64 * seg + 64);      // right halo (before last B)
  __syncthreads();
  do_B(7, rAp, qsAp);

  reduce_losses(4, entA4, comA4, pA4, tid, 4, acc, redE, redC, redP);
  reduce_losses(5, entB, comB, pB, tid, 4, acc, redE, redC, redP);
}

// ---------- P4: finalize 6 scalar losses ----------
__global__ void k_losses(const double* __restrict__ acc, float* __restrict__ out) {
  const int s = threadIdx.x;
  if (s >= 6) return;
  const int pts[6] = {1, 16, 64, 256, 1024, 4096};
  const double n = 128.0 * (double)pts[s];
  const double pse = acc[s] / n;
  const double commit = acc[6 + s] / n;
  double cbe = 0.0;
  for (int c = 0; c < 32; ++c) {
    const double ap = acc[12 + s * 32 + c] / n;
    cbe += -(ap * log(ap + 1e-8) + (1.0 - ap) * log((1.0 - ap) + 1e-8));
  }
  const double pen = (pse - cbe) / 100.0;
  out[s] = (float)(pen * 0.1 + commit * 0.2);
}

extern "C" void kernel_launch(void* const* d_in, const int* in_sizes, int n_in,
                              void* d_out, int out_size, void* d_ws, size_t ws_size,
                              hipStream_t stream) {
  const float* f = (const float*)d_in[0];
  float* qout = (float*)d_out;
  float* bitsOut = qout + QOUT_ELEMS;
  float* lossesOut = qout + (QOUT_ELEMS + BITS_ELEMS);
  float* qv = (float*)d_ws;
  double* acc = (double*)((char*)d_ws + ACC_OFF);
  float* S16 = (float*)((char*)d_ws + S16_OFF);

  hipMemsetAsync(acc, 0, 204 * sizeof(double), stream);
  k_sum16<<<4096, 256, 0, stream>>>(f, S16);
  k_s0<<<NB, 1024, 0, stream>>>(S16, qv, bitsOut, acc);
  k_coarse4<<<NB * 4, 1024, 0, stream>>>(S16, qv, bitsOut, acc);
  k_s45<<<NB * 16, 256, 0, stream>>>(f, qv, qout, bitsOut, acc);
  k_losses<<<1, 64, 0, stream>>>(acc, lossesOut);
}

// Round 10
// 316.813 us; speedup vs baseline: 1.2326x; 1.0121x over previous
//
#include <hip/hip_runtime.h>
#include <hip/hip_bf16.h>
#include <cstddef>
#include <cstdint>

// Problem constants
#define NB 128
#define NT 4096
#define NC 32
// bits rows: scales {1,16,64,256,1024,4096} -> offsets {0,1,17,81,337,1361}, total 5457
#define BITROWS 5457
#define QV_ROWS 1361          // qv region stride (rows 0..336 written)
#define QOUT_ELEMS (NB*NT*NC)             // 16777216
#define BITS_ELEMS (NB*BITROWS*NC)        // 22351872

// ws layout (bytes):
//   qv   @ 0          : NB*1361*32 floats (rows 0..336 per b written)
//   acc  @ 22298624   : 204 doubles (ent[6], com[6], p[6][32]) = 1632 B
//   S16  @ 22302720   : NB*256*32 floats = 4,194,304 B
#define ACC_OFF  22298624
#define S16_OFF  22302720

__device__ __constant__ float kQSC = 0.17677669529663687f;   // 1/sqrt(32)
__device__ __constant__ float kSIG = 17.67766952966369f;     // 100/sqrt(32)

// reference interp against an LDS slice whose row 0 is global coarse row `base`
// (base may be negative; lo>=0 always so indices stay in range). Exact: no fma.
__device__ __forceinline__ float interp_slice(const float* __restrict__ q, int P, int base, int t, int c) {
  float pos = ((float)t + 0.5f) * ((float)P * (1.0f / 4096.0f)) - 0.5f;
  pos = fminf(fmaxf(pos, 0.0f), (float)(P - 1));
  const int lo = (int)pos;
  const int hi = min(lo + 1, P - 1);
  const float w = pos - (float)lo;
  const float a = __fmul_rn(q[(lo - base) * NC + c], 1.0f - w);
  const float b = __fmul_rn(q[(hi - base) * NC + c], w);
  return __fadd_rn(a, b);
}

// the exact reference interp chain with precomputed (lo,hi,w)
__device__ __forceinline__ float interp_w(const float* __restrict__ plo, const float* __restrict__ phi, float w) {
  const float a = __fmul_rn(*plo, 1.0f - w);
  const float b = __fmul_rn(*phi, w);
  return __fadd_rn(a, b);
}

// per-coarse-element: normalize over C (32 lanes), sign-quantize, write qv/bits, loss elems
// qlsRow / qvG are nullable (compile-time constant null folds the store away).
__device__ __forceinline__ void process_elem(
    float msum, float invn, int b, int rowOff, int j, int c,
    float* qlsRow, float* __restrict__ qvG, float* __restrict__ bitsG,
    float& entA, float& comA, float& pA)
{
  const float m = msum * invn;       // invn is a power of two -> exact
  float ss = m * m;
  #pragma unroll
  for (int mk = 16; mk; mk >>= 1) ss += __shfl_xor(ss, mk, 32);
  const float den = fmaxf(sqrtf(ss), 1e-12f);
  const float fn = m / den;
  const bool bit = fn > 0.0f;
  const float zh = bit ? kQSC : -kQSC;
  const float qvv = fn + (zh - fn);  // reference: quantized = f + (zhat - f)
  if (qlsRow) qlsRow[c] = qvv;
  if (qvG) qvG[(size_t)b * (QV_ROWS * NC) + (size_t)(rowOff + j) * NC + c] = qvv;
  bitsG[(size_t)b * (BITROWS * NC) + (size_t)(rowOff + j) * NC + c] = bit ? 1.0f : 0.0f;
  const float arg = (-4.0f * fn) * kSIG;         // sigmoid(-4*f*100/sqrt(32))
  const float p = 1.0f / (1.0f + __expf(-arg));
  const float ent = -(p * __logf(p + 1e-8f) + (1.0f - p) * __logf((1.0f - p) + 1e-8f));
  const float d = qvv - fn;
  entA += ent; comA += d * d; pA += p;
}

// halo version: same quantize chain, no side effects, returns qvv
__device__ __forceinline__ float quant_silent(float msum, float invn) {
  const float m = msum * invn;
  float ss = m * m;
  #pragma unroll
  for (int mk = 16; mk; mk >>= 1) ss += __shfl_xor(ss, mk, 32);
  const float den = fmaxf(sqrtf(ss), 1e-12f);
  const float fn = m / den;
  const float zh = (fn > 0.0f) ? kQSC : -kQSC;
  return fn + (zh - fn);
}

// block-level loss reduction -> double atomics. all threads must call.
__device__ __forceinline__ void reduce_losses(
    int sIdx, float entA, float comA, float pA, int tid, int nWaves,
    double* __restrict__ acc, float* redE, float* redC, float* redP)
{
  float e = entA, cm = comA;
  #pragma unroll
  for (int mk = 32; mk; mk >>= 1) { e += __shfl_xor(e, mk, 64); cm += __shfl_xor(cm, mk, 64); }
  const float p = pA + __shfl_xor(pA, 32, 64);
  const int w = tid >> 6, lane = tid & 63;
  if (lane == 0) { redE[w] = e; redC[w] = cm; }
  if (lane < 32) redP[w * 32 + lane] = p;
  __syncthreads();
  if (tid == 0) {
    double te = 0.0, tc = 0.0;
    for (int i = 0; i < nWaves; ++i) { te += (double)redE[i]; tc += (double)redC[i]; }
    atomicAdd(&acc[sIdx], te);
    atomicAdd(&acc[6 + sIdx], tc);
  }
  if (tid < 32) {
    float tp = 0.0f;
    for (int i = 0; i < nWaves; ++i) tp += redP[i * 32 + tid];
    atomicAdd(&acc[12 + sIdx * 32 + tid], (double)tp);
  }
  __syncthreads();
}

// ---------- P0+P1a fused: granularity-16 sums + scale 0 ----------
// Thread (g=tid>>5, c=tid&31) computes S16 rows [8g, 8g+8) at channel c with the
// identical per-element sum (ascending k), writes them, and accumulates `part`
// in ascending j — exactly the old k_s0 partial order. Bit-identical results.
__global__ __launch_bounds__(1024) void k_s0(
    const float* __restrict__ f, float* __restrict__ S16,
    float* __restrict__ qv, float* __restrict__ bitsOut, double* __restrict__ acc)
{
  __shared__ float red[1024];
  __shared__ float redE[16], redC[16], redP[16 * 32];
  const int b = blockIdx.x, tid = threadIdx.x, c = tid & 31;
  const int g = tid >> 5;
  const float* __restrict__ fbase = f + (size_t)b * (NT * NC);
  float part = 0.0f;
  #pragma unroll
  for (int j = 0; j < 8; ++j) {
    const int row = g * 8 + j;
    const float* p = fbase + (size_t)row * 16 * NC + c;
    float s = 0.0f;
    #pragma unroll
    for (int k = 0; k < 16; ++k) s += p[k * NC];
    S16[(size_t)b * 8192 + (size_t)row * NC + c] = s;
    part += s;                     // ascending j: identical to old k_s0 order
  }
  red[tid] = part;
  __syncthreads();
  float entA = 0.0f, comA = 0.0f, pA = 0.0f;
  if (tid < 32) {
    float msum = 0.0f;
    for (int gg = 0; gg < 32; ++gg) msum += red[gg * 32 + tid];
    process_elem(msum, 1.0f / 4096.0f, b, 0, 0, tid, nullptr, qv, bitsOut, entA, comA, pA);
  }
  reduce_losses(0, entA, comA, pA, tid, 16, acc, redE, redC, redP);
}

// ---------- P1b: scales 1..3, four blocks per batch element (R9) ----------
__global__ __launch_bounds__(1024) void k_coarse4(
    const float* __restrict__ S16g,
    float* __restrict__ qv, float* __restrict__ bitsOut, double* __restrict__ acc)
{
  __shared__ float S[96 * NC];         // rows [64seg-16, 64seg+80), 12 KB
  __shared__ float q1s[6 * NC];        // scale-1 rows [4seg-1, 4seg+5)
  __shared__ float q2s[18 * NC];       // scale-2 rows [16seg-1, 16seg+17)
  __shared__ float redE[16], redC[16], redP[16 * 32];
  const int b = blockIdx.x >> 2, seg = blockIdx.x & 3;
  const int tid = threadIdx.x, c = tid & 31;
  const int s0r = 64 * seg - 16;       // window start (may be negative; clamped slots unread)
  const int base1 = 4 * seg - 1, base2 = 16 * seg - 1;
  const float* __restrict__ sb = S16g + (size_t)b * 8192;
  const float* __restrict__ qb = qv + (size_t)b * (QV_ROWS * NC);

  const float corr = 16.0f * qb[c];
  for (int e = tid; e < 96 * NC; e += 1024) {
    const int rw = min(max(s0r + (e >> 5), 0), 255);
    S[e] = sb[(size_t)rw * NC + (e & 31)] - corr;
  }
  __syncthreads();

  float ent, com, pp;

  // ----- scale 1 (pt=16): 4 own rows + silent halos 4seg-1, 4seg+4 -----
  ent = com = pp = 0.0f;
  if (tid < 6 * NC) {
    const int r = tid >> 5, j = base1 + r;
    if (j >= 0 && j < 16) {
      float msum = 0.0f;
      for (int jj = 0; jj < 16; ++jj) msum += S[(j * 16 + jj - s0r) * NC + c];
      if (r >= 1 && r <= 4)   // own rows [4seg, 4seg+4)
        process_elem(msum, 1.0f / 256.0f, b, 1, j, c, &q1s[r * NC], qv, bitsOut, ent, com, pp);
      else
        q1s[r * NC + c] = quant_silent(msum, 1.0f / 256.0f);
    }
  }
  reduce_losses(1, ent, com, pp, tid, 16, acc, redE, redC, redP);   // publishes q1s

  // scale-1 correction on S rows [64seg-4, 64seg+68)
  for (int e = tid; e < 72 * NC; e += 1024) {
    const int g = 64 * seg - 4 + (e >> 5);
    if (g >= 0 && g < 256) {
      float cs = 0.0f;
      #pragma unroll
      for (int k = 0; k < 16; ++k) cs += interp_slice(q1s, 16, base1, g * 16 + k, c);
      S[(g - s0r) * NC + c] -= cs;
    }
  }
  __syncthreads();

  // ----- scale 2 (pt=64): 16 own rows + silent halos 16seg-1, 16seg+16 -----
  ent = com = pp = 0.0f;
  if (tid < 18 * NC) {
    const int r = tid >> 5, j2 = base2 + r;
    if (j2 >= 0 && j2 < 64) {
      float msum = 0.0f;
      #pragma unroll
      for (int jj = 0; jj < 4; ++jj) msum += S[(j2 * 4 + jj - s0r) * NC + c];
      if (r >= 1 && r <= 16)  // own rows [16seg, 16seg+16)
        process_elem(msum, 1.0f / 64.0f, b, 17, j2, c, &q2s[r * NC], qv, bitsOut, ent, com, pp);
      else
        q2s[r * NC + c] = quant_silent(msum, 1.0f / 64.0f);
    }
  }
  reduce_losses(2, ent, com, pp, tid, 16, acc, redE, redC, redP);   // publishes q2s

  // scale-2 correction on own S rows [64seg, 64seg+64)
  for (int e = tid; e < 64 * NC; e += 1024) {
    const int g = 64 * seg + (e >> 5);
    float cs = 0.0f;
    #pragma unroll
    for (int k = 0; k < 16; ++k) cs += interp_slice(q2s, 64, base2, g * 16 + k, c);
    S[(g - s0r) * NC + c] -= cs;
  }
  __syncthreads();

  // ----- scale 3 (pt=256): 64 own rows -----
  ent = com = pp = 0.0f;
  for (int out = tid; out < 64 * NC; out += 1024) {
    const int g = 64 * seg + (out >> 5);
    process_elem(S[(g - s0r) * NC + c], 1.0f / 16.0f, b, 81, g, c, nullptr, qv, bitsOut, ent, com, pp);
  }
  reduce_losses(3, ent, com, pp, tid, 16, acc, redE, redC, redP);
}

// ---------- P2: scales 4+5 fused, R7 pipeline + integer-derived interp weights ----------
// interp lo/hi/w reconstructed from integer structure of t=4i+k (bit-exact:
// pos is exact in f32 — all terms multiples of 2^-9 with <=13-bit numerators —
// so w = (u+0.5)/D +- 0.5 computed by one exact fma + exact literal add gives
// identical bits; clamp cases at t<=D/2-1, t>=T-D/2 reduce to (lo,hi,0) with the
// same mul/add chain). Rows lo/hi are per-pass constants (k-independent).
__global__ __launch_bounds__(256) void k_s45(
    const float* __restrict__ f, const float* __restrict__ qv,
    float* __restrict__ qout, float* __restrict__ bitsOut, double* __restrict__ acc)
{
  __shared__ float ql0[NC];            // scale0 (P=1): interp == ql0[c] exactly
  __shared__ float q1s[3 * NC];        // scale1 rows [seg-1, seg+1] clamped
  __shared__ float q2s[6 * NC];        // scale2 rows [4seg-1, 4seg+4] clamped
  __shared__ float q3s[18 * NC];       // scale3 rows [16seg-1, 16seg+16] clamped
  __shared__ float ql4[66 * NC];       // scale4 rows [64seg-1, 64seg+64]
  __shared__ float redE[4], redC[4], redP[4 * 32];
  const int b = blockIdx.x >> 4, seg = blockIdx.x & 15;
  const int tid = threadIdx.x, c = tid & 31, rloc = tid >> 5;   // rloc in [0,8)
  const float* __restrict__ qb = qv + (size_t)b * (QV_ROWS * NC);
  const float* __restrict__ fb = f + (size_t)b * (NT * NC);
  const int b1 = seg - 1, b2 = 4 * seg - 1, b3 = 16 * seg - 1, b4 = 64 * seg - 1;
  if (tid < NC) ql0[tid] = qb[tid];
  for (int e = tid; e < 3 * NC; e += 256) {
    const int r = min(max(b1 + (e >> 5), 0), 15);
    q1s[e] = qb[(1 + r) * NC + (e & 31)];
  }
  for (int e = tid; e < 6 * NC; e += 256) {
    const int r = min(max(b2 + (e >> 5), 0), 63);
    q2s[e] = qb[(17 + r) * NC + (e & 31)];
  }
  for (int e = tid; e < 18 * NC; e += 256) {
    const int r = min(max(b3 + (e >> 5), 0), 255);
    q3s[e] = qb[(81 + r) * NC + (e & 31)];
  }
  __syncthreads();

  float entA4 = 0.0f, comA4 = 0.0f, pA4 = 0.0f;   // scale-4 losses
  float entB = 0.0f, comB = 0.0f, pB = 0.0f;      // scale-5 losses

  // Phase-A body: scale-4 row for pass p; fills rc/qc (chain prefixes)
  auto do_A = [&](int p, float rc[4], float qc[4]) {
    const int i = seg * 64 + p * 8 + rloc;
    const float* fp = fb + (size_t)i * 4 * NC + c;

    // ---- per-pass interp setup (k-independent) ----
    // scale 1 (P=16, D=256): global lo = seg-1 (lowhalf) else seg
    const bool lh1 = (i & 63) < 32;
    int rl1 = lh1 ? 0 : 1, rh1;
    float wb1 = __fmaf_rn((float)((i & 63) << 2), 0.00390625f,
                          lh1 ? 0.501953125f : -0.498046875f);
    {
      const bool cz = (seg == 0) && lh1, ch = (seg == 15) && !lh1;
      if (cz) rl1 = 1;
      rh1 = ch ? rl1 : rl1 + 1;
      if (cz || ch) wb1 = -4.0f;   // sentinel: forces w=0 for all k (wb1+k/256 < 0 test)
    }
    // scale 2 (P=64, D=64)
    const int a2r = (i >> 4) & 3;
    const bool lh2 = (i & 15) < 8;
    int rl2 = a2r + (lh2 ? 0 : 1), rh2;
    float wb2 = __fmaf_rn((float)((i & 15) << 2), 0.015625f,
                          lh2 ? 0.5078125f : -0.4921875f);
    {
      const bool cz = (seg == 0) && (a2r == 0) && lh2, ch = (seg == 15) && (a2r == 3) && !lh2;
      if (cz) rl2 = 1;
      rh2 = ch ? rl2 : rl2 + 1;
      if (cz || ch) wb2 = -4.0f;
    }
    // scale 3 (P=256, D=16)
    const int a3r = (i >> 2) & 15;
    const bool lh3 = (i & 3) < 2;
    int rl3 = a3r + (lh3 ? 0 : 1), rh3;
    float wb3 = __fmaf_rn((float)((i & 3) << 2), 0.0625f,
                          lh3 ? 0.53125f : -0.46875f);
    {
      const bool cz = (seg == 0) && (a3r == 0) && lh3, ch = (seg == 15) && (a3r == 15) && !lh3;
      if (cz) rl3 = 1;
      rh3 = ch ? rl3 : rl3 + 1;
      if (cz || ch) wb3 = -4.0f;
    }
    const float* p1lo = &q1s[rl1 * NC + c]; const float* p1hi = &q1s[rh1 * NC + c];
    const float* p2lo = &q2s[rl2 * NC + c]; const float* p2hi = &q2s[rh2 * NC + c];
    const float* p3lo = &q3s[rl3 * NC + c]; const float* p3hi = &q3s[rh3 * NC + c];
    const float q0 = ql0[c];

    float msum = 0.0f;
    #pragma unroll
    for (int k = 0; k < 4; ++k) {
      float w1 = wb1 + (float)k * 0.00390625f; w1 = (w1 < 0.0f) ? 0.0f : w1;
      float w2 = wb2 + (float)k * 0.015625f;   w2 = (w2 < 0.0f) ? 0.0f : w2;
      float w3 = wb3 + (float)k * 0.0625f;     w3 = (w3 < 0.0f) ? 0.0f : w3;
      const float q1 = interp_w(p1lo, p1hi, w1);
      const float q2 = interp_w(p2lo, p2hi, w2);
      const float q3 = interp_w(p3lo, p3hi, w3);
      float r = fp[k * NC];
      r -= q0; r -= q1; r -= q2; r -= q3;                 // exact reference chain prefix
      float qs = q0; qs += q1; qs += q2; qs += q3;        // exact reference qout prefix
      rc[k] = r; qc[k] = qs;
      msum += r;                                          // sequential t-order
    }
    process_elem(msum, 0.25f, b, 337, i, c,
                 &ql4[(size_t)(i - b4) * NC], nullptr, bitsOut, entA4, comA4, pA4);
  };
  // note: interior w's are >0 (odd multiples of 2^-9); sentinel wb=-4 keeps
  // wb+3/16 < 0 -> clamped to exactly 0.0f, matching the reference clamp result.

  // halo row: pure compute into LDS, original interp chain (tiny cost)
  auto do_halo = [&](int hr) {
    const float* fp = fb + (size_t)hr * 4 * NC + c;
    float msum = 0.0f;
    #pragma unroll
    for (int k = 0; k < 4; ++k) {
      const int t = hr * 4 + k;
      float r = fp[k * NC];
      r -= ql0[c];
      r -= interp_slice(q1s, 16,  b1, t, c);
      r -= interp_slice(q2s, 64,  b2, t, c);
      r -= interp_slice(q3s, 256, b3, t, c);
      msum += r;
    }
    ql4[(size_t)(hr - b4) * NC + c] = quant_silent(msum, 0.25f);
  };

  // Phase-B body: scale-5 for pass p using carried prefixes; q4 weights literal
  auto do_B = [&](int p, const float rc[4], const float qc[4]) {
    const int i = seg * 64 + p * 8 + rloc;
    const int ir = p * 8 + rloc;                  // i - 64seg
    const float* r0 = &ql4[(size_t)ir * NC + c];
    const float* r1 = &ql4[(size_t)(ir + 1) * NC + c];
    const float* r2 = &ql4[(size_t)(ir + 2) * NC + c];
    const bool e0 = (i == 0), e1 = (i == 1023);
    #pragma unroll
    for (int k = 0; k < 4; ++k) {
      const float* plo; const float* phi; float w4;
      if (k < 2) {
        plo = e0 ? r1 : r0; phi = e0 ? r2 : r1;
        w4 = e0 ? 0.0f : (k == 0 ? 0.625f : 0.875f);
      } else {
        plo = r1; phi = e1 ? r1 : r2;
        w4 = e1 ? 0.0f : (k == 2 ? 0.125f : 0.375f);
      }
      const float q4 = interp_w(plo, phi, w4);
      float r = rc[k];
      r -= q4;                                            // completes exact chain: fv-q0..-q4
      float qs = qc[k];
      qs += q4;                                           // completes exact qout sum order
      const int t = i * 4 + k;
      float ss = r * r;
      #pragma unroll
      for (int mk = 16; mk; mk >>= 1) ss += __shfl_xor(ss, mk, 32);
      const float den = fmaxf(sqrtf(ss), 1e-12f);
      const float fn = r / den;
      const bool bit = fn > 0.0f;
      const float zh = bit ? kQSC : -kQSC;
      const float qvv = fn + (zh - fn);
      qout[(size_t)b * (NT * NC) + (size_t)t * NC + c] = qs + qvv;
      bitsOut[(size_t)b * (BITROWS * NC) + (size_t)(1361 + t) * NC + c] = bit ? 1.0f : 0.0f;
      const float arg = (-4.0f * fn) * kSIG;
      const float p2 = 1.0f / (1.0f + __expf(-arg));
      entB += -(p2 * __logf(p2 + 1e-8f) + (1.0f - p2) * __logf((1.0f - p2) + 1e-8f));
      const float d = qvv - fn;
      comB += d * d;
      pB += p2;
    }
  };

  float rAp[4], qsAp[4];           // prev-pass carry
  float rAc[4], qsAc[4];           // current-pass carry

  do_A(0, rAp, qsAp);
  if (rloc == 0 && seg > 0) do_halo(64 * seg - 1);        // left halo (with pass 0)

  for (int p = 1; p < 8; ++p) {
    do_A(p, rAc, qsAc);
    __syncthreads();               // ql4 rows of pass p (and p-1) visible
    do_B(p - 1, rAp, qsAp);
    #pragma unroll
    for (int k = 0; k < 4; ++k) { rAp[k] = rAc[k]; qsAp[k] = qsAc[k]; }
  }
  if (rloc == 1 && seg < 15) do_halo(64 * seg + 64);      // right halo (before last B)
  __syncthreads();
  do_B(7, rAp, qsAp);

  reduce_losses(4, entA4, comA4, pA4, tid, 4, acc, redE, redC, redP);
  reduce_losses(5, entB, comB, pB, tid, 4, acc, redE, redC, redP);
}

// ---------- P4: finalize 6 scalar losses ----------
__global__ void k_losses(const double* __restrict__ acc, float* __restrict__ out) {
  const int s = threadIdx.x;
  if (s >= 6) return;
  const int pts[6] = {1, 16, 64, 256, 1024, 4096};
  const double n = 128.0 * (double)pts[s];
  const double pse = acc[s] / n;
  const double commit = acc[6 + s] / n;
  double cbe = 0.0;
  for (int c = 0; c < 32; ++c) {
    const double ap = acc[12 + s * 32 + c] / n;
    cbe += -(ap * log(ap + 1e-8) + (1.0 - ap) * log((1.0 - ap) + 1e-8));
  }
  const double pen = (pse - cbe) / 100.0;
  out[s] = (float)(pen * 0.1 + commit * 0.2);
}

extern "C" void kernel_launch(void* const* d_in, const int* in_sizes, int n_in,
                              void* d_out, int out_size, void* d_ws, size_t ws_size,
                              hipStream_t stream) {
  const float* f = (const float*)d_in[0];
  float* qout = (float*)d_out;
  float* bitsOut = qout + QOUT_ELEMS;
  float* lossesOut = qout + (QOUT_ELEMS + BITS_ELEMS);
  float* qv = (float*)d_ws;
  double* acc = (double*)((char*)d_ws + ACC_OFF);
  float* S16 = (float*)((char*)d_ws + S16_OFF);

  hipMemsetAsync(acc, 0, 204 * sizeof(double), stream);
  k_s0<<<NB, 1024, 0, stream>>>(f, S16, qv, bitsOut, acc);
  k_coarse4<<<NB * 4, 1024, 0, stream>>>(S16, qv, bitsOut, acc);
  k_s45<<<NB * 16, 256, 0, stream>>>(f, qv, qout, bitsOut, acc);
  k_losses<<<1, 64, 0, stream>>>(acc, lossesOut);
}